// Round 2
// baseline (102.138 us; speedup 1.0000x reference)
//
#include <hip/hip_runtime.h>

namespace {

constexpr int BATCH  = 4;
constexpr int SEQ    = 4096;
constexpr int IN_DIM = 64;
constexpr int DM     = 256;
constexpr float ALPHA = 0.1f;   // RES_SCALE

// ---------------------------------------------------------------------------
// Kernel 1: per (batch, chunk) partial X = x_chunk^T x_chunk (64x64) and
// partial column-sum c (64). No atomics -> deterministic.
// ---------------------------------------------------------------------------
__global__ __launch_bounds__(256)
void k_xtx(const float* __restrict__ x, float* __restrict__ Xp,
           float* __restrict__ cp, int nch) {
  const int blk = blockIdx.x;          // = b*nch + ch
  const int b   = blk / nch;
  const int ch  = blk - b * nch;
  const int chrows = SEQ / nch;
  const int t  = threadIdx.x;
  const int tr = t >> 4;               // 0..15
  const int tc = t & 15;               // 0..15

  __shared__ __align__(16) float xs[16][64];
  __shared__ __align__(16) float cs[16][64];

  const float* xb = x + ((size_t)b * SEQ + (size_t)ch * chrows) * IN_DIM;

  float acc[4][4];
#pragma unroll
  for (int i = 0; i < 4; ++i)
#pragma unroll
    for (int j = 0; j < 4; ++j) acc[i][j] = 0.f;
  float4 csum = make_float4(0.f, 0.f, 0.f, 0.f);

  const int nstage = chrows / 16;
  for (int st = 0; st < nstage; ++st) {
    const float4 v = *reinterpret_cast<const float4*>(
        xb + (size_t)(st * 16 + tr) * IN_DIM + tc * 4);
    __syncthreads();
    *reinterpret_cast<float4*>(&xs[tr][tc * 4]) = v;
    csum.x += v.x; csum.y += v.y; csum.z += v.z; csum.w += v.w;
    __syncthreads();
#pragma unroll
    for (int s = 0; s < 16; ++s) {
      const float4 a  = *reinterpret_cast<const float4*>(&xs[s][tr * 4]);
      const float4 bb = *reinterpret_cast<const float4*>(&xs[s][tc * 4]);
      acc[0][0] += a.x * bb.x; acc[0][1] += a.x * bb.y;
      acc[0][2] += a.x * bb.z; acc[0][3] += a.x * bb.w;
      acc[1][0] += a.y * bb.x; acc[1][1] += a.y * bb.y;
      acc[1][2] += a.y * bb.z; acc[1][3] += a.y * bb.w;
      acc[2][0] += a.z * bb.x; acc[2][1] += a.z * bb.y;
      acc[2][2] += a.z * bb.z; acc[2][3] += a.z * bb.w;
      acc[3][0] += a.w * bb.x; acc[3][1] += a.w * bb.y;
      acc[3][2] += a.w * bb.z; acc[3][3] += a.w * bb.w;
    }
  }

  float* Xpb = Xp + (size_t)blk * (64 * 64);
#pragma unroll
  for (int i = 0; i < 4; ++i) {
    const float4 st4 = make_float4(acc[i][0], acc[i][1], acc[i][2], acc[i][3]);
    *reinterpret_cast<float4*>(Xpb + (size_t)(tr * 4 + i) * 64 + tc * 4) = st4;
  }
  *reinterpret_cast<float4*>(&cs[tr][tc * 4]) = csum;
  __syncthreads();
  if (t < 64) {
    float s = 0.f;
#pragma unroll
    for (int g = 0; g < 16; ++g) s += cs[g][t];
    cp[(size_t)blk * 64 + t] = s;
  }
}

// ---------------------------------------------------------------------------
// Chain helpers (1024 threads)
// ---------------------------------------------------------------------------
__device__ __forceinline__ float wave_red(float s) {
  s += __shfl_down(s, 32); s += __shfl_down(s, 16); s += __shfl_down(s, 8);
  s += __shfl_down(s, 4);  s += __shfl_down(s, 2);  s += __shfl_down(s, 1);
  return s;
}

// dst[j] = sum_k v[k] * M[k*DM + j]  (v @ M), K rows in M.
template <int K>
__device__ __forceinline__ void mv_NT(const float* __restrict__ M,
                                      const float* v, float* dst,
                                      float (*pm)[DM], int t) {
  const int ks = t >> 6;      // 16 k-slices
  const int jg = t & 63;
  constexpr int kps = K >> 4;
  float4 acc = make_float4(0.f, 0.f, 0.f, 0.f);
  const float* Mp = M + (size_t)ks * kps * DM + jg * 4;
#pragma unroll
  for (int i = 0; i < kps; ++i) {
    const float  vv = v[ks * kps + i];
    const float4 m  = *reinterpret_cast<const float4*>(Mp + (size_t)i * DM);
    acc.x += vv * m.x; acc.y += vv * m.y; acc.z += vv * m.z; acc.w += vv * m.w;
  }
  *reinterpret_cast<float4*>(&pm[ks][jg * 4]) = acc;
  __syncthreads();
  if (t < DM) {
    float s = 0.f;
#pragma unroll
    for (int g = 0; g < 16; ++g) s += pm[g][t];
    dst[t] = s;
  }
  __syncthreads();
}

// dst[r] = dot(v, M[r,:]) for r < R  (v @ M^T).
template <int R>
__device__ __forceinline__ void mv_TN(const float* __restrict__ M,
                                      const float* v, float* dst, int t) {
  const int w = t >> 6, l = t & 63;
  const float4 vv = *reinterpret_cast<const float4*>(v + l * 4);
  constexpr int rpw = R >> 4;
#pragma unroll
  for (int i = 0; i < rpw; ++i) {
    const int r = w * rpw + i;
    const float4 m = *reinterpret_cast<const float4*>(M + (size_t)r * DM + l * 4);
    float s = m.x * vv.x + m.y * vv.y + m.z * vv.z + m.w * vv.w;
    s = wave_red(s);
    if (l == 0) dst[r] = s;
  }
  __syncthreads();
}

// dst = v @ G0, G0 = Wemb^T X Wemb + u b^T + b u^T + SEQ b b^T (factored).
__device__ __forceinline__ void G0app(const float* v, float* dst,
    const float* __restrict__ Wemb, const float (*Xs)[64],
    const float* u, const float* bsv,
    float* r1, float* r2, float (*pm)[DM], float (*pms)[64],
    float* scal, int t) {
  mv_TN<64>(Wemb, v, r1, t);                 // r1 = v @ Wemb^T
  const int w = t >> 6, l = t & 63;
  if (w < 2) {                               // scal = {v.u, v.b}
    const float* o = (w == 0) ? u : bsv;
    const float4 a  = *reinterpret_cast<const float4*>(v + l * 4);
    const float4 bb = *reinterpret_cast<const float4*>(o + l * 4);
    float s = a.x * bb.x + a.y * bb.y + a.z * bb.z + a.w * bb.w;
    s = wave_red(s);
    if (l == 0) scal[w] = s;
  }
  __syncthreads();
  if (t < 256) {                             // r2 = r1 @ X
    const int ks = t >> 6, j = t & 63;
    float s = 0.f;
#pragma unroll
    for (int i = 0; i < 16; ++i) s += r1[ks * 16 + i] * Xs[ks * 16 + i][j];
    pms[ks][j] = s;
  }
  __syncthreads();
  if (t < 64) r2[t] = pms[0][t] + pms[1][t] + pms[2][t] + pms[3][t];
  __syncthreads();
  mv_NT<64>(Wemb, r2, dst, pm, t);           // dst = r2 @ Wemb
  if (t < DM)
    dst[t] += scal[0] * bsv[t] + scal[1] * u[t] + (float)SEQ * scal[1] * bsv[t];
  __syncthreads();
}

// ---------------------------------------------------------------------------
// Kernel 2: one block per batch. Vector chain with output folding:
//   out = s1.Wout + a*(z2.wv1o) + a^2*(d2.wv01o) + bout
// where wv1o = Wv1@Wout, wv01o = Wv0@wv1o.
// ---------------------------------------------------------------------------
__global__ __launch_bounds__(1024)
void k_chain(const float* __restrict__ Xp, const float* __restrict__ cp,
             const float* __restrict__ Wemb, const float* __restrict__ bemb,
             const float* __restrict__ Wq, const float* __restrict__ Wk,
             const float* __restrict__ Wv, const float* __restrict__ Wout,
             const float* __restrict__ bout, float* __restrict__ out, int nch) {
  const int b = blockIdx.x;
  const int t = threadIdx.x;

  __shared__ __align__(16) float Xs[64][64];
  __shared__ __align__(16) float pm[16][DM];
  __shared__ __align__(16) float pms[4][64];
  __shared__ __align__(16) float vecU[DM], vecS0[DM], vecS1[DM];
  __shared__ __align__(16) float T1[DM], T2[DM], T3[DM];
  __shared__ __align__(16) float wv1o[DM], wv01o[DM], wouts[DM], bs[DM];
  __shared__ __align__(16) float cvec[64], r1[64], r2[64];
  __shared__ float scal[2], dots[3];

  // ---- prologue: reduce partials, stage small vectors
  {
    float4 a = make_float4(0.f, 0.f, 0.f, 0.f);
    for (int ch = 0; ch < nch; ++ch) {
      const float4 p = *reinterpret_cast<const float4*>(
          Xp + (size_t)(b * nch + ch) * 4096 + t * 4);
      a.x += p.x; a.y += p.y; a.z += p.z; a.w += p.w;
    }
    *reinterpret_cast<float4*>(&Xs[0][0] + t * 4) = a;
    if (t < 64) {
      float s = 0.f;
      for (int ch = 0; ch < nch; ++ch) s += cp[(size_t)(b * nch + ch) * 64 + t];
      cvec[t] = s;
    }
    if (t < DM) { bs[t] = bemb[t]; wouts[t] = Wout[t]; }
  }
  __syncthreads();

  const float* Wq0 = Wq;  const float* Wq1 = Wq + DM * DM;
  const float* Wk0 = Wk;  const float* Wk1 = Wk + DM * DM;
  const float* Wv0 = Wv;  const float* Wv1 = Wv + DM * DM;

  // u = c @ Wemb ; s0 = u + SEQ*b
  mv_NT<64>(Wemb, cvec, vecU, pm, t);
  if (t < DM) vecS0[t] = vecU[t] + (float)SEQ * bs[t];
  __syncthreads();

  // output-fold vectors: wv1o = Wv1 @ Wout ; wv01o = Wv0 @ wv1o
  mv_TN<DM>(Wv1, wouts, wv1o, t);
  mv_TN<DM>(Wv0, wv1o, wv01o, t);

  // ---- layer 0: s1 = s0 + a*((((s0 Wq0) Wk0^T) G0) Wv0)
  mv_NT<DM>(Wq0, vecS0, T1, pm, t);                          // a1
  mv_TN<DM>(Wk0, T1, T2, t);                                 // a1 @ Wk0^T
  G0app(T2, T1, Wemb, Xs, vecU, bs, r1, r2, pm, pms, scal, t); // a2
  mv_NT<DM>(Wv0, T1, T2, pm, t);                             // a3
  if (t < DM) vecS1[t] = vecS0[t] + ALPHA * T2[t];
  __syncthreads();

  // ---- layer 1 (folded): v1 = s1 Wq1 Wk1^T ; z = v1 A0^T ; z2 = z G0 ;
  //                        d2 = ((z2 Wq0) Wk0^T) G0
  mv_NT<DM>(Wq1, vecS1, T1, pm, t);
  mv_TN<DM>(Wk1, T1, T2, t);                                 // v1 (keep in T2)
  mv_TN<DM>(Wv0, T2, T1, t);                                 // c1 = v1 @ Wv0^T
  G0app(T1, T3, Wemb, Xs, vecU, bs, r1, r2, pm, pms, scal, t); // c2
  mv_NT<DM>(Wk0, T3, T1, pm, t);                             // c3a = c2 @ Wk0
  mv_TN<DM>(Wq0, T1, T3, t);                                 // c3 = c3a @ Wq0^T
  if (t < DM) T1[t] = T2[t] + ALPHA * T3[t];                 // z = v1 + a*c3
  __syncthreads();
  G0app(T1, T2, Wemb, Xs, vecU, bs, r1, r2, pm, pms, scal, t); // z2 (keep in T2)
  mv_NT<DM>(Wq0, T2, T1, pm, t);                             // d1a = z2 @ Wq0
  mv_TN<DM>(Wk0, T1, T3, t);                                 // d1 = d1a @ Wk0^T
  G0app(T3, T1, Wemb, Xs, vecU, bs, r1, r2, pm, pms, scal, t); // d2 (in T1)

  // ---- out = s1.wout + a*(z2.wv1o) + a^2*(d2.wv01o) + bout
  const int w = t >> 6, l = t & 63;
  if (w < 3) {
    const float* pa = (w == 0) ? vecS1 : (w == 1) ? T2 : T1;
    const float* pb = (w == 0) ? wouts : (w == 1) ? wv1o : wv01o;
    const float4 a = *reinterpret_cast<const float4*>(pa + l * 4);
    const float4 c = *reinterpret_cast<const float4*>(pb + l * 4);
    float s = a.x * c.x + a.y * c.y + a.z * c.z + a.w * c.w;
    s = wave_red(s);
    if (l == 0) dots[w] = s;
  }
  __syncthreads();
  if (t == 0)
    out[b] = dots[0] + ALPHA * dots[1] + (ALPHA * ALPHA) * dots[2] + bout[0];
}

}  // namespace

extern "C" void kernel_launch(void* const* d_in, const int* in_sizes, int n_in,
                              void* d_out, int out_size, void* d_ws, size_t ws_size,
                              hipStream_t stream) {
  const float* x    = (const float*)d_in[0];
  const float* Wemb = (const float*)d_in[1];
  const float* bemb = (const float*)d_in[2];
  const float* Wq   = (const float*)d_in[3];
  const float* Wk   = (const float*)d_in[4];
  const float* Wv   = (const float*)d_in[5];
  const float* Wout = (const float*)d_in[6];
  const float* bout = (const float*)d_in[7];
  float* out = (float*)d_out;

  int nch = 32;
  while (nch > 1 &&
         (size_t)(BATCH * nch) * (4096 + 64) * sizeof(float) > ws_size)
    nch >>= 1;

  float* Xp = (float*)d_ws;                       // [B*nch][64*64]
  float* cp = Xp + (size_t)BATCH * nch * 4096;    // [B*nch][64]

  k_xtx<<<BATCH * nch, 256, 0, stream>>>(x, Xp, cp, nch);
  k_chain<<<BATCH, 1024, 0, stream>>>(Xp, cp, Wemb, bemb, Wq, Wk, Wv,
                                      Wout, bout, out, nch);
}

// Round 3
// 61.204 us; speedup vs baseline: 1.6688x; 1.6688x over previous
//
#include <hip/hip_runtime.h>

namespace {

constexpr int BATCH = 4, SEQ = 4096, DM = 256, DP = 80;  // DP: padded 65-dim
constexpr float ALPHA = 0.1f;

__device__ __forceinline__ float dot4(float4 a, float4 b) {
  return a.x * b.x + a.y * b.y + a.z * b.z + a.w * b.w;
}

// ---------------------------------------------------------------------------
// K1: per (batch, chunk) partial x^T x (64x64) + column sums. Deterministic.
// ---------------------------------------------------------------------------
__global__ __launch_bounds__(256)
void k_xtx(const float* __restrict__ x, float* __restrict__ Xp,
           float* __restrict__ cp, int nch) {
  const int blk = blockIdx.x;
  const int b = blk / nch, ch = blk - b * nch;
  const int chrows = SEQ / nch;
  const int t = threadIdx.x, tr = t >> 4, tc = t & 15;

  __shared__ __align__(16) float xs[16][64];
  __shared__ __align__(16) float cs[16][64];

  const float* xb = x + ((size_t)b * SEQ + (size_t)ch * chrows) * 64;

  float acc[4][4];
#pragma unroll
  for (int i = 0; i < 4; ++i)
#pragma unroll
    for (int j = 0; j < 4; ++j) acc[i][j] = 0.f;
  float4 csum = make_float4(0.f, 0.f, 0.f, 0.f);

  const int nstage = chrows / 16;
  for (int st = 0; st < nstage; ++st) {
    const float4 v = *reinterpret_cast<const float4*>(
        xb + (size_t)(st * 16 + tr) * 64 + tc * 4);
    __syncthreads();
    *reinterpret_cast<float4*>(&xs[tr][tc * 4]) = v;
    csum.x += v.x; csum.y += v.y; csum.z += v.z; csum.w += v.w;
    __syncthreads();
#pragma unroll
    for (int s = 0; s < 16; ++s) {
      const float4 a = *reinterpret_cast<const float4*>(&xs[s][tr * 4]);
      const float4 bb = *reinterpret_cast<const float4*>(&xs[s][tc * 4]);
      acc[0][0] += a.x * bb.x; acc[0][1] += a.x * bb.y;
      acc[0][2] += a.x * bb.z; acc[0][3] += a.x * bb.w;
      acc[1][0] += a.y * bb.x; acc[1][1] += a.y * bb.y;
      acc[1][2] += a.y * bb.z; acc[1][3] += a.y * bb.w;
      acc[2][0] += a.z * bb.x; acc[2][1] += a.z * bb.y;
      acc[2][2] += a.z * bb.z; acc[2][3] += a.z * bb.w;
      acc[3][0] += a.w * bb.x; acc[3][1] += a.w * bb.y;
      acc[3][2] += a.w * bb.z; acc[3][3] += a.w * bb.w;
    }
  }
  float* Xpb = Xp + (size_t)blk * 4096;
#pragma unroll
  for (int i = 0; i < 4; ++i) {
    const float4 s4 = make_float4(acc[i][0], acc[i][1], acc[i][2], acc[i][3]);
    *reinterpret_cast<float4*>(Xpb + (size_t)(tr * 4 + i) * 64 + tc * 4) = s4;
  }
  *reinterpret_cast<float4*>(&cs[tr][tc * 4]) = csum;
  __syncthreads();
  if (t < 64) {
    float s = 0.f;
#pragma unroll
    for (int g = 0; g < 16; ++g) s += cs[g][t];
    cp[(size_t)blk * 64 + t] = s;
  }
}

// ---------------------------------------------------------------------------
// K2: roles by blockIdx:
//  [0,64): QK tiles (64x32): QK_l[i][j] = dot(Wq_l[i,:], Wk_l[j,:])
//  [64,129): F0t rows: F0t[j][i] = (Ebar @ Wv0)[i][j]
//  129: Et build (Et[k][i] = Ebar[i][k]) + zero pads of all t-matrices
//  [130,134): Xbar (80x80, padded) + cbar per batch, from Xp/cp partials
//  134: w1 = Wv1 @ Wout
// ---------------------------------------------------------------------------
__global__ __launch_bounds__(256)
void k_pre1(const float* __restrict__ Wemb, const float* __restrict__ bemb,
            const float* __restrict__ Wq, const float* __restrict__ Wk,
            const float* __restrict__ Wv, const float* __restrict__ Wout,
            const float* __restrict__ Xp, const float* __restrict__ cp,
            float* __restrict__ QK0, float* __restrict__ QK1,
            float* __restrict__ Et, float* __restrict__ F0t,
            float* __restrict__ Z0t, float* __restrict__ Z1t,
            float* __restrict__ Y1t, float* __restrict__ Xb,
            float* __restrict__ cb, float* __restrict__ w1, int nch) {
  const int bid = blockIdx.x, t = threadIdx.x;
  __shared__ __align__(16) float sm[12672];  // 50.7 KB, aliased per role

  if (bid < 64) {
    // ---- QK dot-tiles ----
    const int mat = bid >> 5, qq = bid & 31;
    const int a0 = (qq >> 3) * 64, b0 = (qq & 7) * 32;
    const float* Aw = Wq + (size_t)mat * DM * DM;
    const float* Bw = Wk + (size_t)mat * DM * DM;
    float* C = mat ? QK1 : QK0;
    float* Als = sm;                 // [64][132]
    float* Bls = sm + 64 * 132;      // [32][132]
    float acc[4][2] = {{0.f, 0.f}, {0.f, 0.f}, {0.f, 0.f}, {0.f, 0.f}};
    const int lr = t >> 7, lc = t & 127;
    for (int kc = 0; kc < DM; kc += 128) {
      __syncthreads();
      for (int rr = 0; rr < 32; ++rr)
        Als[(rr * 2 + lr) * 132 + lc] = Aw[(size_t)(a0 + rr * 2 + lr) * DM + kc + lc];
      for (int rr = 0; rr < 16; ++rr)
        Bls[(rr * 2 + lr) * 132 + lc] = Bw[(size_t)(b0 + rr * 2 + lr) * DM + kc + lc];
      __syncthreads();
      const int jj = (t & 15) * 2, og = t >> 4;
      for (int k = 0; k < 128; k += 4) {
        const float4 bv0 = *reinterpret_cast<const float4*>(&Bls[jj * 132 + k]);
        const float4 bv1 = *reinterpret_cast<const float4*>(&Bls[(jj + 1) * 132 + k]);
#pragma unroll
        for (int m = 0; m < 4; ++m) {
          const float4 av =
              *reinterpret_cast<const float4*>(&Als[(og + 16 * m) * 132 + k]);
          acc[m][0] += dot4(av, bv0);
          acc[m][1] += dot4(av, bv1);
        }
      }
    }
    const int jj = (t & 15) * 2, og = t >> 4;
#pragma unroll
    for (int m = 0; m < 4; ++m) {
      C[(size_t)(a0 + og + 16 * m) * DM + b0 + jj] = acc[m][0];
      C[(size_t)(a0 + og + 16 * m) * DM + b0 + jj + 1] = acc[m][1];
    }
  } else if (bid < 129) {
    // ---- F0t row i = (Ebar Wv0) row i, written transposed ----
    const int i = bid - 64;
    float* Els = sm;            // [256]
    float* pms = sm + 256;      // [4][256]
    Els[t] = (i < 64) ? Wemb[(size_t)i * DM + t] : bemb[t];
    __syncthreads();
    const int jj = t & 63, ks = t >> 6;
    float4 acc = make_float4(0.f, 0.f, 0.f, 0.f);
    for (int k = ks * 64; k < ks * 64 + 64; ++k) {
      const float e = Els[k];
      const float4 w = *reinterpret_cast<const float4*>(&Wv[(size_t)k * DM + jj * 4]);
      acc.x += e * w.x; acc.y += e * w.y; acc.z += e * w.z; acc.w += e * w.w;
    }
    *reinterpret_cast<float4*>(&pms[ks * 256 + jj * 4]) = acc;
    __syncthreads();
    F0t[(size_t)t * DP + i] =
        pms[t] + pms[256 + t] + pms[512 + t] + pms[768 + t];
  } else if (bid == 129) {
    // ---- Et + zero all pads ----
    for (int i = 0; i < 64; ++i) Et[(size_t)t * DP + i] = Wemb[(size_t)i * DM + t];
    Et[(size_t)t * DP + 64] = bemb[t];
    for (int i = 65; i < DP; ++i) {
      Et[(size_t)t * DP + i] = 0.f;
      F0t[(size_t)t * DP + i] = 0.f;
      Z0t[(size_t)t * DP + i] = 0.f;
      Z1t[(size_t)t * DP + i] = 0.f;
      Y1t[(size_t)t * DP + i] = 0.f;
    }
  } else if (bid < 134) {
    // ---- Xbar + cbar for batch b ----
    const int b = bid - 130;
    float* cv = sm;  // [64]
    float4 acc[4];
#pragma unroll
    for (int m = 0; m < 4; ++m) acc[m] = make_float4(0.f, 0.f, 0.f, 0.f);
    for (int ch = 0; ch < nch; ++ch) {
      const float* P = Xp + (size_t)(b * nch + ch) * 4096;
#pragma unroll
      for (int m = 0; m < 4; ++m) {
        const float4 p = *reinterpret_cast<const float4*>(&P[(m * 256 + t) * 4]);
        acc[m].x += p.x; acc[m].y += p.y; acc[m].z += p.z; acc[m].w += p.w;
      }
    }
    float* XB = Xb + (size_t)b * 6400;
#pragma unroll
    for (int m = 0; m < 4; ++m) {
      const int e4 = m * 256 + t, r = e4 >> 4, c4 = (e4 & 15) * 4;
      *reinterpret_cast<float4*>(&XB[r * 80 + c4]) = acc[m];
    }
    if (t < 64) {
      float s = 0.f;
      for (int ch = 0; ch < nch; ++ch) s += cp[(size_t)(b * nch + ch) * 64 + t];
      cv[t] = s;
    }
    __syncthreads();
    if (t < 64) { XB[t * 80 + 64] = cv[t]; XB[64 * 80 + t] = cv[t]; }
    if (t == 0) XB[64 * 80 + 64] = (float)SEQ;
    for (int idx = t; idx < 6400; idx += 256) {
      const int r = idx / 80, c = idx - r * 80;
      if (r > 64 || c > 64) XB[idx] = 0.f;
    }
    if (t < DP) cb[b * DP + t] = (t < 64) ? cv[t] : (t == 64 ? (float)SEQ : 0.f);
  } else {
    // ---- w1 = Wv1 @ Wout ----
    float* wos = sm;
    wos[t] = Wout[t];
    __syncthreads();
    const float* Wv1 = Wv + (size_t)DM * DM;
    float s = 0.f;
    for (int u = 0; u < 64; ++u)
      s += dot4(*reinterpret_cast<const float4*>(&Wv1[(size_t)t * DM + u * 4]),
                *reinterpret_cast<const float4*>(&wos[u * 4]));
    w1[t] = s;
  }
}

// ---------------------------------------------------------------------------
// K3: Z0 = Ebar@QK0, Z1 = Ebar@QK1, Y1 = F0bar@QK1 — row-form, stored transposed
// ---------------------------------------------------------------------------
__global__ __launch_bounds__(256)
void k_pre2(const float* __restrict__ Wemb, const float* __restrict__ bemb,
            const float* __restrict__ QK0, const float* __restrict__ QK1,
            const float* __restrict__ F0t, float* __restrict__ Z0t,
            float* __restrict__ Z1t, float* __restrict__ Y1t) {
  const int bid = blockIdx.x, t = threadIdx.x;
  const int r = bid / 65, i = bid % 65;
  __shared__ __align__(16) float Els[256];
  __shared__ __align__(16) float pms[4][256];
  if (r == 2) Els[t] = F0t[(size_t)t * DP + i];
  else        Els[t] = (i < 64) ? Wemb[(size_t)i * DM + t] : bemb[t];
  __syncthreads();
  const float* M = (r == 0) ? QK0 : QK1;
  float* D = (r == 0) ? Z0t : (r == 1) ? Z1t : Y1t;
  const int jj = t & 63, ks = t >> 6;
  float4 acc = make_float4(0.f, 0.f, 0.f, 0.f);
  for (int k = ks * 64; k < ks * 64 + 64; ++k) {
    const float e = Els[k];
    const float4 w = *reinterpret_cast<const float4*>(&M[(size_t)k * DM + jj * 4]);
    acc.x += e * w.x; acc.y += e * w.y; acc.z += e * w.z; acc.w += e * w.w;
  }
  *reinterpret_cast<float4*>(&pms[ks][jj * 4]) = acc;
  __syncthreads();
  D[(size_t)t * DP + i] = pms[0][t] + pms[1][t] + pms[2][t] + pms[3][t];
}

// ---------------------------------------------------------------------------
// K4 helpers (1024 threads; every helper ends in a full-block barrier)
// ---------------------------------------------------------------------------
__device__ __forceinline__ void colT(const float* __restrict__ Mt,
                                     const float* coef, float* dst,
                                     float (*pm)[DP], int t) {
  // dst[i<80] = sum_k coef[k] * Mt[k*DP+i]
  const int i = t % DP, ks = t / DP;
  if (ks < 8) {
    float a = 0.f;
    for (int k = ks * 32; k < ks * 32 + 32; ++k) a += coef[k] * Mt[(size_t)k * DP + i];
    pm[ks][i] = a;
  }
  __syncthreads();
  if (t < DP) {
    float s = 0.f;
#pragma unroll
    for (int q = 0; q < 8; ++q) s += pm[q][t];
    dst[t] = s;
  }
  __syncthreads();
}

__device__ __forceinline__ void colT2(const float* __restrict__ Mt,
                                      const float* c1, const float* c2,
                                      float* d1, float* d2, float (*pmA)[DP],
                                      float (*pmB)[DP], int t) {
  const int i = t % DP, ks = t / DP;
  if (ks < 8) {
    float a = 0.f, b = 0.f;
    for (int k = ks * 32; k < ks * 32 + 32; ++k) {
      const float m = Mt[(size_t)k * DP + i];
      a += c1[k] * m; b += c2[k] * m;
    }
    pmA[ks][i] = a; pmB[ks][i] = b;
  }
  __syncthreads();
  if (t < DP) {
    float sa = 0.f, sb = 0.f;
#pragma unroll
    for (int q = 0; q < 8; ++q) { sa += pmA[q][t]; sb += pmB[q][t]; }
    d1[t] = sa; d2[t] = sb;
  }
  __syncthreads();
}

__device__ __forceinline__ void colE(const float* __restrict__ Wemb,
                                     const float* __restrict__ bemb,
                                     const float* c80, float* dst256, int t) {
  // dst[j<256] = sum_{i<65} c80[i] * Ebar[i][j]
  if (t < 256) {
    float a = 0.f;
    for (int i = 0; i < 64; ++i) a += c80[i] * Wemb[(size_t)i * DM + t];
    a += c80[64] * bemb[t];
    dst256[t] = a;
  }
  __syncthreads();
}

__device__ __forceinline__ void xvL(const float (*X)[81], const float* v,
                                    float* o, int t) {
  // o[j<80] = sum_i v[i] * X[i][j]
  if (t < DP) {
    float s = 0.f;
    for (int i = 0; i < DP; ++i) s += v[i] * X[i][t];
    o[t] = s;
  }
  __syncthreads();
}

__device__ __forceinline__ void xvR(const float (*X)[81], const float* v,
                                    float* o, int t) {
  // o[i<80] = sum_j X[i][j] * v[j]
  if (t < DP) {
    float s = 0.f;
    for (int j = 0; j < DP; ++j) s += X[t][j] * v[j];
    o[t] = s;
  }
  __syncthreads();
}

// ---------------------------------------------------------------------------
// K4: one block per batch — the whole per-batch chain in 65/80-dim space
// ---------------------------------------------------------------------------
__global__ __launch_bounds__(1024)
void k_final(const float* __restrict__ Wemb, const float* __restrict__ bemb,
             const float* __restrict__ Wout, const float* __restrict__ bout,
             const float* __restrict__ Et, const float* __restrict__ F0t,
             const float* __restrict__ Z0t, const float* __restrict__ Z1t,
             const float* __restrict__ Y1t, const float* __restrict__ Xb,
             const float* __restrict__ cb, const float* __restrict__ w1g,
             float* __restrict__ out) {
  const int b = blockIdx.x, t = threadIdx.x;
  __shared__ __align__(16) float Xls[DP][81];
  __shared__ __align__(16) float pmA[8][DP], pmB[8][DP];
  __shared__ __align__(16) float v256[256], v256b[256];
  __shared__ __align__(16) float wol[256], w1l[256];
  __shared__ __align__(16) float cbl[DP], e_o[DP], e1v[DP], f0v[DP], f1v[DP];
  __shared__ __align__(16) float cM0[DP], g[DP], rE[DP], rF[DP], t1[DP];
  __shared__ __align__(16) float yv[DP], qv[DP], pv[DP], Xq[DP], zv[DP];
  __shared__ float pr[3][DP];

  for (int idx = t; idx < 6400; idx += 1024)
    Xls[idx / 80][idx % 80] = Xb[(size_t)b * 6400 + idx];
  if (t < DP) cbl[t] = cb[b * DP + t];
  if (t < 256) wol[t] = Wout[t];
  else if (t < 512) w1l[t - 256] = w1g[t - 256];
  __syncthreads();

  colT2(Et, wol, w1l, e_o, e1v, pmA, pmB, t);   // e_o = Ebar wo ; e1 = Ebar w1
  colT2(F0t, wol, w1l, f0v, f1v, pmA, pmB, t);  // f0 = F0bar wo ; f1 = F0bar w1

  // a = cbar @ Z0  (256)
  if (t < 256) {
    const float4* Z = reinterpret_cast<const float4*>(Z0t + (size_t)t * DP);
    float s = 0.f;
#pragma unroll
    for (int u = 0; u < 20; ++u)
      s += dot4(Z[u], *reinterpret_cast<const float4*>(&cbl[u * 4]));
    v256[t] = s;
  }
  __syncthreads();
  colT(Et, v256, cM0, pmA, t);   // cM0 = a Ebar^T  (= cbar M0)
  xvL(Xls, cM0, g, t);           // g = cM0 Xbar

  // hv = cbar@Z1 + ALPHA * g@Y1  (256)
  if (t < 256) {
    const float4* Z1 = reinterpret_cast<const float4*>(Z1t + (size_t)t * DP);
    const float4* Y1 = reinterpret_cast<const float4*>(Y1t + (size_t)t * DP);
    float s1 = 0.f, s2 = 0.f;
#pragma unroll
    for (int u = 0; u < 20; ++u) {
      s1 += dot4(Z1[u], *reinterpret_cast<const float4*>(&cbl[u * 4]));
      s2 += dot4(Y1[u], *reinterpret_cast<const float4*>(&g[u * 4]));
    }
    v256b[t] = s1 + ALPHA * s2;
  }
  __syncthreads();
  colT(Et, v256b, rE, pmA, t);   // rE = h Ebar^T
  colT(F0t, v256b, rF, pmA, t);  // rF = h F0bar^T
  xvL(Xls, rF, t1, t);           // t1 = rF Xbar
  colE(Wemb, bemb, t1, v256, t); // t2 = t1 Ebar  (256)
  colT(Z0t, v256, zv, pmA, t);   // zv = t2 Z0^T
  if (t < DP) pv[t] = rE[t] + ALPHA * zv[t];   // p
  __syncthreads();
  xvR(Xls, f1v, yv, t);          // y = Xbar f1
  colE(Wemb, bemb, yv, v256b, t);// z2 = y Ebar  (256)
  colT(Z0t, v256b, zv, pmA, t);  // zv = z2 Z0^T
  if (t < DP) qv[t] = e1v[t] + ALPHA * zv[t];  // q
  __syncthreads();
  xvR(Xls, qv, Xq, t);           // Xq = Xbar q

  if (t < 3 * DP) {
    const int grp = t / DP, i = t % DP;
    const float* a = grp == 0 ? cbl : grp == 1 ? g : pv;
    const float* c = grp == 0 ? e_o : grp == 1 ? f0v : Xq;
    pr[grp][i] = a[i] * c[i];
  }
  __syncthreads();
  if (t == 0) {
    float s0 = 0.f, s1 = 0.f, s2 = 0.f;
    for (int i = 0; i < DP; ++i) { s0 += pr[0][i]; s1 += pr[1][i]; s2 += pr[2][i]; }
    out[b] = s0 + ALPHA * s1 + ALPHA * s2 + bout[0];
  }
}

}  // namespace

extern "C" void kernel_launch(void* const* d_in, const int* in_sizes, int n_in,
                              void* d_out, int out_size, void* d_ws, size_t ws_size,
                              hipStream_t stream) {
  const float* x    = (const float*)d_in[0];
  const float* Wemb = (const float*)d_in[1];
  const float* bemb = (const float*)d_in[2];
  const float* Wq   = (const float*)d_in[3];
  const float* Wk   = (const float*)d_in[4];
  const float* Wv   = (const float*)d_in[5];
  const float* Wout = (const float*)d_in[6];
  const float* bout = (const float*)d_in[7];
  float* out = (float*)d_out;

  int nch = 16;
  auto need = [](int n) -> size_t {
    return ((size_t)BATCH * n * 4096 + (size_t)BATCH * n * 64 + 2 * 65536 +
            5 * (256 * DP) + BATCH * 6400 + BATCH * DP + 256) * sizeof(float);
  };
  while (nch > 4 && need(nch) > ws_size) nch >>= 1;

  float* p = (float*)d_ws;
  float* Xp  = p; p += (size_t)BATCH * nch * 4096;
  float* cp  = p; p += (size_t)BATCH * nch * 64;
  float* QK0 = p; p += 65536;
  float* QK1 = p; p += 65536;
  float* Et  = p; p += 256 * DP;
  float* F0t = p; p += 256 * DP;
  float* Z0t = p; p += 256 * DP;
  float* Z1t = p; p += 256 * DP;
  float* Y1t = p; p += 256 * DP;
  float* Xb  = p; p += BATCH * 6400;
  float* cb  = p; p += BATCH * DP;
  float* w1  = p; p += 256;

  k_xtx<<<BATCH * nch, 256, 0, stream>>>(x, Xp, cp, nch);
  k_pre1<<<135, 256, 0, stream>>>(Wemb, bemb, Wq, Wk, Wv, Wout, Xp, cp, QK0, QK1,
                                  Et, F0t, Z0t, Z1t, Y1t, Xb, cb, w1, nch);
  k_pre2<<<195, 256, 0, stream>>>(Wemb, bemb, QK0, QK1, F0t, Z0t, Z1t, Y1t);
  k_final<<<4, 1024, 0, stream>>>(Wemb, bemb, Wout, bout, Et, F0t, Z0t, Z1t, Y1t,
                                  Xb, cb, w1, out);
}